// Round 4
// baseline (764.735 us; speedup 1.0000x reference)
//
#include <hip/hip_runtime.h>
#include <hip/hip_fp16.h>

#define NPIX   512
#define NDET   768
#define NSAMP  768
#define NVIEW  360
#define NBATCH 8
#define ZSPLIT 4

typedef _Float16 v2h __attribute__((ext_vector_type(2)));

#if defined(__has_builtin)
#if __has_builtin(__builtin_amdgcn_fdot2)
#define USE_FDOT2 1
#endif
#endif

__device__ __forceinline__ float dot2f(v2h a, v2h b, float c) {
#ifdef USE_FDOT2
    return __builtin_amdgcn_fdot2(a, b, c, false);
#else
    return fmaf((float)a.x, (float)b.x, fmaf((float)a.y, (float)b.y, c));
#endif
}

// ---------------------------------------------------------------------------
// Repack image [8,512,512] fp32 -> pair-dup fp16 [512y][512x][8b] of half2:
//   elem(y,x,b) = ( v[b][y][x], v[b][y][min(x+1,511)] )
// One pixel row-corner = 32 B = two int4 loads; bilinear becomes dot2 ops.
// ---------------------------------------------------------------------------
__global__ __launch_bounds__(256) void repack_kernel(
    const float* __restrict__ image,    // [8, 512, 512]
    __half2* __restrict__ packed)       // [512*512, 8] half2
{
    const int idx = blockIdx.x * blockDim.x + threadIdx.x;  // (y<<9)|x
    if (idx >= NPIX * NPIX) return;
    const int x  = idx & (NPIX - 1);
    const int x1 = min(x + 1, NPIX - 1);
    const int base = idx - x;           // y<<9
#pragma unroll
    for (int b = 0; b < NBATCH; ++b) {
        const float* img = image + (size_t)b * (NPIX * NPIX);
        packed[(size_t)idx * NBATCH + b] =
            __floats2half2_rn(img[base + x], img[base + x1]);
    }
}

// ---------------------------------------------------------------------------
// Main projector: thread = (view, det); blockIdx.z splits samples 4-way.
// Per sample: 4 dwordx4 loads + 16 v_dot2_f32_f16. atomicAdd into zeroed out.
// ---------------------------------------------------------------------------
__global__ __launch_bounds__(256) void projector_kernel(
    const int4* __restrict__ pk,        // [512*512][2] int4 (8 half2 per pixel)
    const float* __restrict__ views,    // [360]
    float* __restrict__ out)            // [8, 360, 768]
{
    const int d = blockIdx.x * blockDim.x + threadIdx.x;
    const int v = blockIdx.y;
    const int z = blockIdx.z;
    if (d >= NDET) return;

    const float PIX   = 0.7433f;
    const float ISO   = 595.0f;
    const float SDD_  = 595.0f + 490.6f;          // 1085.6
    const float DGAM  = 1.2858f / SDD_;
    const float FOV   = 512.0f * 0.7433f * 0.70710678f;
    const float T0    = ISO - FOV;
    const float DT    = 2.0f * FOV / (float)NSAMP;

    const float beta  = views[v];
    const float gamma = ((float)d - 0.5f * (float)(NDET - 1)) * DGAM;
    const float sx = ISO * cosf(beta);
    const float sy = ISO * sinf(beta);
    const float ang = beta + 3.14159265358979f + gamma;
    const float gx = cosf(ang) / PIX;
    const float gy = sinf(ang) / PIX;
    const float cx = sx / PIX + 0.5f * (float)(NPIX - 1);
    const float cy = sy / PIX + 0.5f * (float)(NPIX - 1);

    // Clip sample range to padded image box (pad 3 px; outside contributes 0)
    const float PLO = -3.0f, PHI = (float)NPIX + 2.0f;
    float lo = T0 + 0.5f * DT;
    float hi = T0 + ((float)NSAMP - 0.5f) * DT;
    if (fabsf(gx) > 1e-8f) {
        float ta = (PLO - cx) / gx, tb = (PHI - cx) / gx;
        lo = fmaxf(lo, fminf(ta, tb));
        hi = fminf(hi, fmaxf(ta, tb));
    } else if (cx < PLO || cx > PHI) {
        hi = lo - 1.0f;
    }
    if (fabsf(gy) > 1e-8f) {
        float ta = (PLO - cy) / gy, tb = (PHI - cy) / gy;
        lo = fmaxf(lo, fminf(ta, tb));
        hi = fminf(hi, fmaxf(ta, tb));
    } else if (cy < PLO || cy > PHI) {
        hi = lo - 1.0f;
    }

    int s_begin = 0, s_end = 0;
    if (hi >= lo) {
        s_begin = max(0, (int)floorf((lo - T0) / DT - 0.5f));
        s_end   = min(NSAMP, (int)ceilf((hi - T0) / DT - 0.5f) + 1);
    }

    // split [s_begin, s_end) into ZSPLIT chunks by blockIdx.z
    const int len   = s_end - s_begin;
    const int chunk = (len + ZSPLIT - 1) / ZSPLIT;
    const int cs    = s_begin + z * chunk;
    const int ce    = min(s_end, cs + chunk);

    float acc[NBATCH];
#pragma unroll
    for (int b = 0; b < NBATCH; ++b) acc[b] = 0.0f;

    for (int s = cs; s < ce; ++s) {
        const float t  = fmaf((float)s + 0.5f, DT, T0);
        const float fx = fmaf(gx, t, cx);
        const float fy = fmaf(gy, t, cy);
        const float x0f = floorf(fx);
        const float y0f = floorf(fy);
        const float wx = fx - x0f;
        const float wy = fy - y0f;
        const int ix = (int)x0f;
        const int iy = (int)y0f;
        const float ax = 1.0f - wx;
        const float ay = 1.0f - wy;

        const bool vx0 = (unsigned)ix        < (unsigned)NPIX;
        const bool vx1 = (unsigned)(ix + 1)  < (unsigned)NPIX;
        const bool vy0 = (unsigned)iy        < (unsigned)NPIX;
        const bool vy1 = (unsigned)(iy + 1)  < (unsigned)NPIX;

        float w00 = (vx0 && vy0) ? ax * ay : 0.0f;
        float w01 = (vx1 && vy0) ? wx * ay : 0.0f;
        float w10 = (vx0 && vy1) ? ax * wy : 0.0f;
        float w11 = (vx1 && vy1) ? wx * wy : 0.0f;

        // pair layout holds (v[xc0], v[xc0+1]); when ix<0 the valid corner
        // (x=0) sits in the pair's FIRST slot -> shift weights left.
        const bool xneg = (ix < 0);
        const float s00 = xneg ? w01 : w00;
        const float s01 = xneg ? 0.0f : w01;
        const float s10 = xneg ? w11 : w10;
        const float s11 = xneg ? 0.0f : w11;

        const int xc0 = min(max(ix, 0), NPIX - 1);
        const int yc0 = min(max(iy,     0), NPIX - 1);
        const int yc1 = min(max(iy + 1, 0), NPIX - 1);

        union { __half2 h; v2h v; } wAu, wBu;
        wAu.h = __floats2half2_rn(s00, s01);
        wBu.h = __floats2half2_rn(s10, s11);
        const v2h wA = wAu.v;
        const v2h wB = wBu.v;

        const int p0 = (((yc0 << 9) + xc0) << 1);   // int4 index, 2 per pixel
        const int p1 = (((yc1 << 9) + xc0) << 1);

        union { int4 i; v2h h[4]; } q0, q1, q2, q3;
        q0.i = pk[p0];       // row y0, batches 0-3
        q1.i = pk[p0 + 1];   // row y0, batches 4-7
        q2.i = pk[p1];       // row y1, batches 0-3
        q3.i = pk[p1 + 1];   // row y1, batches 4-7

#pragma unroll
        for (int k = 0; k < 4; ++k) {
            acc[k]     = dot2f(q0.h[k], wA, acc[k]);
            acc[k]     = dot2f(q2.h[k], wB, acc[k]);
            acc[k + 4] = dot2f(q1.h[k], wA, acc[k + 4]);
            acc[k + 4] = dot2f(q3.h[k], wB, acc[k + 4]);
        }
    }

#pragma unroll
    for (int b = 0; b < NBATCH; ++b) {
        atomicAdd(&out[((size_t)b * NVIEW + v) * NDET + d], acc[b] * DT);
    }
}

// ---------------------------------------------------------------------------
// Fallback (original layout, fp32 scalar loads) if ws is too small.
// ---------------------------------------------------------------------------
__global__ __launch_bounds__(256) void projector_kernel_fallback(
    const float* __restrict__ image, const float* __restrict__ views,
    float* __restrict__ out)
{
    const int d = blockIdx.x * blockDim.x + threadIdx.x;
    const int v = blockIdx.y;
    if (d >= NDET) return;

    const float PIX = 0.7433f, ISO = 595.0f;
    const float SDD_ = 595.0f + 490.6f;
    const float DGAM = 1.2858f / SDD_;
    const float FOV  = 512.0f * 0.7433f * 0.70710678f;
    const float T0   = ISO - FOV;
    const float DT   = 2.0f * FOV / (float)NSAMP;

    const float beta  = views[v];
    const float gamma = ((float)d - 0.5f * (float)(NDET - 1)) * DGAM;
    const float sx = ISO * cosf(beta), sy = ISO * sinf(beta);
    const float ang = beta + 3.14159265358979f + gamma;
    const float gx = cosf(ang) / PIX, gy = sinf(ang) / PIX;
    const float cx = sx / PIX + 0.5f * (float)(NPIX - 1);
    const float cy = sy / PIX + 0.5f * (float)(NPIX - 1);

    float acc[NBATCH];
#pragma unroll
    for (int b = 0; b < NBATCH; ++b) acc[b] = 0.0f;

    for (int s = 0; s < NSAMP; ++s) {
        const float t  = fmaf((float)s + 0.5f, DT, T0);
        const float fx = fmaf(gx, t, cx);
        const float fy = fmaf(gy, t, cy);
        const float x0f = floorf(fx), y0f = floorf(fy);
        const float wx = fx - x0f, wy = fy - y0f;
        const int ix = (int)x0f, iy = (int)y0f;
        const float ax = 1.0f - wx, ay = 1.0f - wy;
        const bool vx0 = (unsigned)ix < (unsigned)NPIX;
        const bool vx1 = (unsigned)(ix + 1) < (unsigned)NPIX;
        const bool vy0 = (unsigned)iy < (unsigned)NPIX;
        const bool vy1 = (unsigned)(iy + 1) < (unsigned)NPIX;
        const float w00 = (vx0 && vy0) ? ax * ay : 0.0f;
        const float w01 = (vx1 && vy0) ? wx * ay : 0.0f;
        const float w10 = (vx0 && vy1) ? ax * wy : 0.0f;
        const float w11 = (vx1 && vy1) ? wx * wy : 0.0f;
        const int xc0 = min(max(ix, 0), NPIX - 1);
        const int xc1 = min(max(ix + 1, 0), NPIX - 1);
        const int yc0 = min(max(iy, 0), NPIX - 1);
        const int yc1 = min(max(iy + 1, 0), NPIX - 1);
        const int i00 = (yc0 << 9) + xc0, i01 = (yc0 << 9) + xc1;
        const int i10 = (yc1 << 9) + xc0, i11 = (yc1 << 9) + xc1;
#pragma unroll
        for (int b = 0; b < NBATCH; ++b) {
            const float* img = image + (size_t)b * (NPIX * NPIX);
            acc[b] = fmaf(w00, img[i00], fmaf(w01, img[i01],
                     fmaf(w10, img[i10], fmaf(w11, img[i11], acc[b]))));
        }
    }
#pragma unroll
    for (int b = 0; b < NBATCH; ++b)
        out[((size_t)b * NVIEW + v) * NDET + d] = acc[b] * DT;
}

extern "C" void kernel_launch(void* const* d_in, const int* in_sizes, int n_in,
                              void* d_out, int out_size, void* d_ws, size_t ws_size,
                              hipStream_t stream) {
    const float* image = (const float*)d_in[0];
    const float* views = (const float*)d_in[1];
    float* out = (float*)d_out;

    const size_t packed_bytes = (size_t)NPIX * NPIX * NBATCH * sizeof(__half2);

    if (ws_size >= packed_bytes && d_ws != nullptr) {
        __half2* packed = (__half2*)d_ws;
        repack_kernel<<<dim3((NPIX * NPIX) / 256), dim3(256), 0, stream>>>(image, packed);
        hipMemsetAsync(out, 0, (size_t)out_size * sizeof(float), stream);
        projector_kernel<<<dim3(NDET / 256, NVIEW, ZSPLIT), dim3(256), 0, stream>>>(
            (const int4*)packed, views, out);
    } else {
        projector_kernel_fallback<<<dim3(NDET / 256, NVIEW), dim3(256), 0, stream>>>(image, views, out);
    }
}

// Round 5
// 641.918 us; speedup vs baseline: 1.1913x; 1.1913x over previous
//
#include <hip/hip_runtime.h>
#include <hip/hip_fp16.h>

#define NPIX   512
#define NDET   768
#define NSAMP  768
#define NVIEW  360
#define NBATCH 8
#define ZSPLIT 4

// ---------------------------------------------------------------------------
// Repack image [8,512,512] fp32 -> packed fp16 [512*512, 8] (batch-innermost).
// One pixel's 8 batch values = 16 B = one dwordx4 per bilinear corner.
// Total 4 MB -> resident in each XCD's 4 MB L2 (R4 lesson: 8 MB thrashes).
// ---------------------------------------------------------------------------
__global__ __launch_bounds__(256) void repack_kernel(
    const float* __restrict__ image,    // [8, 512, 512]
    __half* __restrict__ packed)        // [512*512, 8]
{
    const int idx = blockIdx.x * blockDim.x + threadIdx.x;  // (y<<9)|x
    if (idx >= NPIX * NPIX) return;
    union { __half h[8]; int4 v; } u;
#pragma unroll
    for (int b = 0; b < NBATCH; ++b)
        u.h[b] = __float2half_rn(image[(size_t)b * (NPIX * NPIX) + idx]);
    ((int4*)packed)[idx] = u.v;
}

// fp16 source folded into fp32 fma -> v_fma_mix_f32 (no separate cvt)
__device__ __forceinline__ void acc_corner(const int4 raw, const float w,
                                           float acc[NBATCH]) {
    union { int4 i; _Float16 h[8]; } u;
    u.i = raw;
#pragma unroll
    for (int b = 0; b < NBATCH; ++b)
        acc[b] = fmaf((float)u.h[b], w, acc[b]);
}

// ---------------------------------------------------------------------------
// Main projector: thread = (view, det); blockIdx.z splits samples 4-way.
// Loop split: border samples (clamped/validity-weighted) vs interior samples
// (no clamps, no selects). atomicAdd into zeroed out.
// ---------------------------------------------------------------------------
__global__ __launch_bounds__(256) void projector_kernel(
    const int4* __restrict__ pk,        // [512*512] int4 (8 half per pixel)
    const float* __restrict__ views,    // [360]
    float* __restrict__ out)            // [8, 360, 768]
{
    const int d = blockIdx.x * blockDim.x + threadIdx.x;
    const int v = blockIdx.y;
    const int z = blockIdx.z;
    if (d >= NDET) return;

    const float PIX   = 0.7433f;
    const float ISO   = 595.0f;
    const float SDD_  = 595.0f + 490.6f;          // 1085.6
    const float DGAM  = 1.2858f / SDD_;
    const float FOV   = 512.0f * 0.7433f * 0.70710678f;
    const float T0    = ISO - FOV;
    const float DT    = 2.0f * FOV / (float)NSAMP;

    const float beta  = views[v];
    const float gamma = ((float)d - 0.5f * (float)(NDET - 1)) * DGAM;
    const float sx = ISO * cosf(beta);
    const float sy = ISO * sinf(beta);
    const float ang = beta + 3.14159265358979f + gamma;
    const float gx = cosf(ang) / PIX;
    const float gy = sinf(ang) / PIX;
    const float cx = sx / PIX + 0.5f * (float)(NPIX - 1);
    const float cy = sy / PIX + 0.5f * (float)(NPIX - 1);

    // ---- clip sample range to padded image box (pad 3 px; outside = 0) ----
    const float PLO = -3.0f, PHI = (float)NPIX + 2.0f;
    float lo = T0 + 0.5f * DT;
    float hi = T0 + ((float)NSAMP - 0.5f) * DT;
    if (fabsf(gx) > 1e-8f) {
        float ta = (PLO - cx) / gx, tb = (PHI - cx) / gx;
        lo = fmaxf(lo, fminf(ta, tb));
        hi = fminf(hi, fmaxf(ta, tb));
    } else if (cx < PLO || cx > PHI) {
        hi = lo - 1.0f;
    }
    if (fabsf(gy) > 1e-8f) {
        float ta = (PLO - cy) / gy, tb = (PHI - cy) / gy;
        lo = fmaxf(lo, fminf(ta, tb));
        hi = fminf(hi, fmaxf(ta, tb));
    } else if (cy < PLO || cy > PHI) {
        hi = lo - 1.0f;
    }

    int s_begin = 0, s_end = 0;
    if (hi >= lo) {
        s_begin = max(0, (int)floorf((lo - T0) / DT - 0.5f));
        s_end   = min(NSAMP, (int)ceilf((hi - T0) / DT - 0.5f) + 1);
    }

    // ---- interior range: strictly inside [0.01, 510.99]^2 (no clamping) ---
    const float XLO = 0.01f, XHI = 510.99f;
    float ilo = lo, ihi = hi;
    if (fabsf(gx) > 1e-8f) {
        float ta = (XLO - cx) / gx, tb = (XHI - cx) / gx;
        ilo = fmaxf(ilo, fminf(ta, tb));
        ihi = fminf(ihi, fmaxf(ta, tb));
    } else if (cx < XLO || cx > XHI) {
        ihi = ilo - 1.0f;
    }
    if (fabsf(gy) > 1e-8f) {
        float ta = (XLO - cy) / gy, tb = (XHI - cy) / gy;
        ilo = fmaxf(ilo, fminf(ta, tb));
        ihi = fminf(ihi, fmaxf(ta, tb));
    } else if (cy < XLO || cy > XHI) {
        ihi = ilo - 1.0f;
    }

    int ib = s_begin, ie = s_begin;   // empty interior default (full coverage
                                      // then falls to the two border loops)
    if (ihi >= ilo) {
        ib = max(s_begin, (int)ceilf ((ilo - T0) / DT - 0.5f));
        ie = min(s_end,   (int)floorf((ihi - T0) / DT - 0.5f) + 1);
        if (ie < ib) { ib = s_begin; ie = s_begin; }
    }

    // ---- this block's chunk of [s_begin, s_end) ---------------------------
    const int len   = s_end - s_begin;
    const int chunk = (len + ZSPLIT - 1) / ZSPLIT;
    const int cs    = s_begin + z * chunk;
    const int ce    = min(s_end, cs + chunk);

    // precompute fx(s) = fxs*sf + fx0 with sf = (float)s (exact float counter)
    const float fxs = gx * DT;
    const float fys = gy * DT;
    const float fx0 = fmaf(gx, T0 + 0.5f * DT, cx);
    const float fy0 = fmaf(gy, T0 + 0.5f * DT, cy);

    float acc[NBATCH];
#pragma unroll
    for (int b = 0; b < NBATCH; ++b) acc[b] = 0.0f;

    // ---------------- border loop 1: [cs, min(ce, ib)) ---------------------
    {
        const int e1 = min(ce, ib);
        float sf = (float)cs;
        for (int s = cs; s < e1; ++s, sf += 1.0f) {
            const float fx = fmaf(fxs, sf, fx0);
            const float fy = fmaf(fys, sf, fy0);
            const float x0f = floorf(fx), y0f = floorf(fy);
            const float wx = fx - x0f, wy = fy - y0f;
            const int ix = (int)x0f, iy = (int)y0f;
            const float ax = 1.0f - wx, ay = 1.0f - wy;
            const bool vx0 = (unsigned)ix       < (unsigned)NPIX;
            const bool vx1 = (unsigned)(ix + 1) < (unsigned)NPIX;
            const bool vy0 = (unsigned)iy       < (unsigned)NPIX;
            const bool vy1 = (unsigned)(iy + 1) < (unsigned)NPIX;
            const float w00 = (vx0 && vy0) ? ax * ay : 0.0f;
            const float w01 = (vx1 && vy0) ? wx * ay : 0.0f;
            const float w10 = (vx0 && vy1) ? ax * wy : 0.0f;
            const float w11 = (vx1 && vy1) ? wx * wy : 0.0f;
            const int xc0 = min(max(ix,     0), NPIX - 1);
            const int xc1 = min(max(ix + 1, 0), NPIX - 1);
            const int yc0 = min(max(iy,     0), NPIX - 1);
            const int yc1 = min(max(iy + 1, 0), NPIX - 1);
            acc_corner(pk[(yc0 << 9) + xc0], w00, acc);
            acc_corner(pk[(yc0 << 9) + xc1], w01, acc);
            acc_corner(pk[(yc1 << 9) + xc0], w10, acc);
            acc_corner(pk[(yc1 << 9) + xc1], w11, acc);
        }
    }

    // ---------------- interior loop: [max(cs,ib), min(ce,ie)) --------------
    {
        const int s0 = max(cs, ib), s1 = min(ce, ie);
        float sf = (float)s0;
        for (int s = s0; s < s1; ++s, sf += 1.0f) {
            const float fx = fmaf(fxs, sf, fx0);
            const float fy = fmaf(fys, sf, fy0);
            const float x0f = floorf(fx), y0f = floorf(fy);
            const float wx = fx - x0f, wy = fy - y0f;
            const int ix = (int)x0f, iy = (int)y0f;
            const float ax = 1.0f - wx, ay = 1.0f - wy;
            const float w00 = ax * ay;
            const float w01 = wx * ay;
            const float w10 = ax * wy;
            const float w11 = wx * wy;
            const int p0 = (iy << 9) + ix;       // row y0, col x0
            const int p1 = p0 + NPIX;            // row y0+1
            acc_corner(pk[p0],     w00, acc);
            acc_corner(pk[p0 + 1], w01, acc);
            acc_corner(pk[p1],     w10, acc);
            acc_corner(pk[p1 + 1], w11, acc);
        }
    }

    // ---------------- border loop 2: [max(cs, ie), ce) ---------------------
    {
        const int s0 = max(cs, ie);
        float sf = (float)s0;
        for (int s = s0; s < ce; ++s, sf += 1.0f) {
            const float fx = fmaf(fxs, sf, fx0);
            const float fy = fmaf(fys, sf, fy0);
            const float x0f = floorf(fx), y0f = floorf(fy);
            const float wx = fx - x0f, wy = fy - y0f;
            const int ix = (int)x0f, iy = (int)y0f;
            const float ax = 1.0f - wx, ay = 1.0f - wy;
            const bool vx0 = (unsigned)ix       < (unsigned)NPIX;
            const bool vx1 = (unsigned)(ix + 1) < (unsigned)NPIX;
            const bool vy0 = (unsigned)iy       < (unsigned)NPIX;
            const bool vy1 = (unsigned)(iy + 1) < (unsigned)NPIX;
            const float w00 = (vx0 && vy0) ? ax * ay : 0.0f;
            const float w01 = (vx1 && vy0) ? wx * ay : 0.0f;
            const float w10 = (vx0 && vy1) ? ax * wy : 0.0f;
            const float w11 = (vx1 && vy1) ? wx * wy : 0.0f;
            const int xc0 = min(max(ix,     0), NPIX - 1);
            const int xc1 = min(max(ix + 1, 0), NPIX - 1);
            const int yc0 = min(max(iy,     0), NPIX - 1);
            const int yc1 = min(max(iy + 1, 0), NPIX - 1);
            acc_corner(pk[(yc0 << 9) + xc0], w00, acc);
            acc_corner(pk[(yc0 << 9) + xc1], w01, acc);
            acc_corner(pk[(yc1 << 9) + xc0], w10, acc);
            acc_corner(pk[(yc1 << 9) + xc1], w11, acc);
        }
    }

#pragma unroll
    for (int b = 0; b < NBATCH; ++b) {
        atomicAdd(&out[((size_t)b * NVIEW + v) * NDET + d], acc[b] * DT);
    }
}

// ---------------------------------------------------------------------------
// Fallback (original layout, fp32 scalar loads) if ws is too small.
// ---------------------------------------------------------------------------
__global__ __launch_bounds__(256) void projector_kernel_fallback(
    const float* __restrict__ image, const float* __restrict__ views,
    float* __restrict__ out)
{
    const int d = blockIdx.x * blockDim.x + threadIdx.x;
    const int v = blockIdx.y;
    if (d >= NDET) return;

    const float PIX = 0.7433f, ISO = 595.0f;
    const float SDD_ = 595.0f + 490.6f;
    const float DGAM = 1.2858f / SDD_;
    const float FOV  = 512.0f * 0.7433f * 0.70710678f;
    const float T0   = ISO - FOV;
    const float DT   = 2.0f * FOV / (float)NSAMP;

    const float beta  = views[v];
    const float gamma = ((float)d - 0.5f * (float)(NDET - 1)) * DGAM;
    const float sx = ISO * cosf(beta), sy = ISO * sinf(beta);
    const float ang = beta + 3.14159265358979f + gamma;
    const float gx = cosf(ang) / PIX, gy = sinf(ang) / PIX;
    const float cx = sx / PIX + 0.5f * (float)(NPIX - 1);
    const float cy = sy / PIX + 0.5f * (float)(NPIX - 1);

    float acc[NBATCH];
#pragma unroll
    for (int b = 0; b < NBATCH; ++b) acc[b] = 0.0f;

    for (int s = 0; s < NSAMP; ++s) {
        const float t  = fmaf((float)s + 0.5f, DT, T0);
        const float fx = fmaf(gx, t, cx);
        const float fy = fmaf(gy, t, cy);
        const float x0f = floorf(fx), y0f = floorf(fy);
        const float wx = fx - x0f, wy = fy - y0f;
        const int ix = (int)x0f, iy = (int)y0f;
        const float ax = 1.0f - wx, ay = 1.0f - wy;
        const bool vx0 = (unsigned)ix < (unsigned)NPIX;
        const bool vx1 = (unsigned)(ix + 1) < (unsigned)NPIX;
        const bool vy0 = (unsigned)iy < (unsigned)NPIX;
        const bool vy1 = (unsigned)(iy + 1) < (unsigned)NPIX;
        const float w00 = (vx0 && vy0) ? ax * ay : 0.0f;
        const float w01 = (vx1 && vy0) ? wx * ay : 0.0f;
        const float w10 = (vx0 && vy1) ? ax * wy : 0.0f;
        const float w11 = (vx1 && vy1) ? wx * wy : 0.0f;
        const int xc0 = min(max(ix, 0), NPIX - 1);
        const int xc1 = min(max(ix + 1, 0), NPIX - 1);
        const int yc0 = min(max(iy, 0), NPIX - 1);
        const int yc1 = min(max(iy + 1, 0), NPIX - 1);
        const int i00 = (yc0 << 9) + xc0, i01 = (yc0 << 9) + xc1;
        const int i10 = (yc1 << 9) + xc0, i11 = (yc1 << 9) + xc1;
#pragma unroll
        for (int b = 0; b < NBATCH; ++b) {
            const float* img = image + (size_t)b * (NPIX * NPIX);
            acc[b] = fmaf(w00, img[i00], fmaf(w01, img[i01],
                     fmaf(w10, img[i10], fmaf(w11, img[i11], acc[b]))));
        }
    }
#pragma unroll
    for (int b = 0; b < NBATCH; ++b)
        out[((size_t)b * NVIEW + v) * NDET + d] = acc[b] * DT;
}

extern "C" void kernel_launch(void* const* d_in, const int* in_sizes, int n_in,
                              void* d_out, int out_size, void* d_ws, size_t ws_size,
                              hipStream_t stream) {
    const float* image = (const float*)d_in[0];
    const float* views = (const float*)d_in[1];
    float* out = (float*)d_out;

    const size_t packed_bytes = (size_t)NPIX * NPIX * NBATCH * sizeof(__half);

    if (ws_size >= packed_bytes && d_ws != nullptr) {
        __half* packed = (__half*)d_ws;
        repack_kernel<<<dim3((NPIX * NPIX) / 256), dim3(256), 0, stream>>>(image, packed);
        hipMemsetAsync(out, 0, (size_t)out_size * sizeof(float), stream);
        projector_kernel<<<dim3(NDET / 256, NVIEW, ZSPLIT), dim3(256), 0, stream>>>(
            (const int4*)packed, views, out);
    } else {
        projector_kernel_fallback<<<dim3(NDET / 256, NVIEW), dim3(256), 0, stream>>>(image, views, out);
    }
}

// Round 6
// 560.761 us; speedup vs baseline: 1.3637x; 1.1447x over previous
//
#include <hip/hip_runtime.h>
#include <hip/hip_fp16.h>

#define NPIX   512
#define NDET   768
#define NSAMP  768
#define NVIEW  360
#define NBATCH 8

// ---------------------------------------------------------------------------
// Repack image [8,512,512] fp32 -> packed fp16 [512*512, 8] (batch-innermost).
// One pixel's 8 batch values = 16 B = one dwordx4 per bilinear corner.
// Total 4 MB -> resident in each XCD's 4 MB L2 (R4 lesson: 8 MB thrashes).
// ---------------------------------------------------------------------------
__global__ __launch_bounds__(256) void repack_kernel(
    const float* __restrict__ image,    // [8, 512, 512]
    __half* __restrict__ packed)        // [512*512, 8]
{
    const int idx = blockIdx.x * blockDim.x + threadIdx.x;  // (y<<9)|x
    if (idx >= NPIX * NPIX) return;
    union { __half h[8]; int4 v; } u;
#pragma unroll
    for (int b = 0; b < NBATCH; ++b)
        u.h[b] = __float2half_rn(image[(size_t)b * (NPIX * NPIX) + idx]);
    ((int4*)packed)[idx] = u.v;
}

// fp16 source folded into fp32 fma -> v_fma_mix_f32 (no separate cvt)
__device__ __forceinline__ void acc_corner(const int4 raw, const float w,
                                           float acc[NBATCH]) {
    union { int4 i; _Float16 h[8]; } u;
    u.i = raw;
#pragma unroll
    for (int b = 0; b < NBATCH; ++b)
        acc[b] = fmaf((float)u.h[b], w, acc[b]);
}

// ---------------------------------------------------------------------------
// Main projector. Lane remap for gather locality:
//   wave = 16 detectors x 4 sample-offsets  (lane = soff*16 + detlane)
// so one wave-gather touches a ~15px x 4px patch instead of a 60px 1D locus
// (fewer distinct 128B lines per instruction -> less L1 issue serialization).
// The 4 soff threads per det partition samples (s = begin+soff, step 4) and
// are reduced in-wave via shfl_xor; lane<16 stores (no atomics, no memset).
// ---------------------------------------------------------------------------
__global__ __launch_bounds__(256) void projector_kernel(
    const int4* __restrict__ pk,        // [512*512] int4 (8 half per pixel)
    const float* __restrict__ views,    // [360]
    float* __restrict__ out)            // [8, 360, 768]
{
    const int lane    = threadIdx.x & 63;
    const int wave    = threadIdx.x >> 6;        // 0..3
    const int detlane = lane & 15;
    const int soff    = lane >> 4;               // 0..3
    const int d = blockIdx.x * 64 + wave * 16 + detlane;   // < 768 always
    const int v = blockIdx.y;

    const float PIX   = 0.7433f;
    const float ISO   = 595.0f;
    const float SDD_  = 595.0f + 490.6f;          // 1085.6
    const float DGAM  = 1.2858f / SDD_;
    const float FOV   = 512.0f * 0.7433f * 0.70710678f;
    const float T0    = ISO - FOV;
    const float DT    = 2.0f * FOV / (float)NSAMP;

    const float beta  = views[v];
    const float gamma = ((float)d - 0.5f * (float)(NDET - 1)) * DGAM;
    const float sx = ISO * cosf(beta);
    const float sy = ISO * sinf(beta);
    const float ang = beta + 3.14159265358979f + gamma;
    const float gx = cosf(ang) / PIX;
    const float gy = sinf(ang) / PIX;
    const float cx = sx / PIX + 0.5f * (float)(NPIX - 1);
    const float cy = sy / PIX + 0.5f * (float)(NPIX - 1);

    // ---- clip sample range to padded image box (pad 3 px; outside = 0) ----
    const float PLO = -3.0f, PHI = (float)NPIX + 2.0f;
    float lo = T0 + 0.5f * DT;
    float hi = T0 + ((float)NSAMP - 0.5f) * DT;
    if (fabsf(gx) > 1e-8f) {
        float ta = (PLO - cx) / gx, tb = (PHI - cx) / gx;
        lo = fmaxf(lo, fminf(ta, tb));
        hi = fminf(hi, fmaxf(ta, tb));
    } else if (cx < PLO || cx > PHI) {
        hi = lo - 1.0f;
    }
    if (fabsf(gy) > 1e-8f) {
        float ta = (PLO - cy) / gy, tb = (PHI - cy) / gy;
        lo = fmaxf(lo, fminf(ta, tb));
        hi = fminf(hi, fmaxf(ta, tb));
    } else if (cy < PLO || cy > PHI) {
        hi = lo - 1.0f;
    }

    int s_begin = 0, s_end = 0;
    if (hi >= lo) {
        s_begin = max(0, (int)floorf((lo - T0) / DT - 0.5f));
        s_end   = min(NSAMP, (int)ceilf((hi - T0) / DT - 0.5f) + 1);
    }

    // ---- interior range: strictly inside [0.01, 510.99]^2 (no clamping) ---
    const float XLO = 0.01f, XHI = 510.99f;
    float ilo = lo, ihi = hi;
    if (fabsf(gx) > 1e-8f) {
        float ta = (XLO - cx) / gx, tb = (XHI - cx) / gx;
        ilo = fmaxf(ilo, fminf(ta, tb));
        ihi = fminf(ihi, fmaxf(ta, tb));
    } else if (cx < XLO || cx > XHI) {
        ihi = ilo - 1.0f;
    }
    if (fabsf(gy) > 1e-8f) {
        float ta = (XLO - cy) / gy, tb = (XHI - cy) / gy;
        ilo = fmaxf(ilo, fminf(ta, tb));
        ihi = fminf(ihi, fmaxf(ta, tb));
    } else if (cy < XLO || cy > XHI) {
        ihi = ilo - 1.0f;
    }

    int ib = s_begin, ie = s_begin;   // empty interior default
    if (ihi >= ilo) {
        ib = max(s_begin, (int)ceilf ((ilo - T0) / DT - 0.5f));
        ie = min(s_end,   (int)floorf((ihi - T0) / DT - 0.5f) + 1);
        if (ie < ib) { ib = s_begin; ie = s_begin; }
    }

    // fx(s) = fxs*s + fx0
    const float fxs = gx * DT;
    const float fys = gy * DT;
    const float fx0 = fmaf(gx, T0 + 0.5f * DT, cx);
    const float fy0 = fmaf(gy, T0 + 0.5f * DT, cy);

    float acc[NBATCH];
#pragma unroll
    for (int b = 0; b < NBATCH; ++b) acc[b] = 0.0f;

    int s = s_begin + soff;          // this thread's samples: step 4

    // ---------------- border loop 1: s < ib --------------------------------
    for (; s < ib; s += 4) {
        const float sf = (float)s;
        const float fx = fmaf(fxs, sf, fx0);
        const float fy = fmaf(fys, sf, fy0);
        const float x0f = floorf(fx), y0f = floorf(fy);
        const float wx = fx - x0f, wy = fy - y0f;
        const int ix = (int)x0f, iy = (int)y0f;
        const float ax = 1.0f - wx, ay = 1.0f - wy;
        const bool vx0 = (unsigned)ix       < (unsigned)NPIX;
        const bool vx1 = (unsigned)(ix + 1) < (unsigned)NPIX;
        const bool vy0 = (unsigned)iy       < (unsigned)NPIX;
        const bool vy1 = (unsigned)(iy + 1) < (unsigned)NPIX;
        const float w00 = (vx0 && vy0) ? ax * ay : 0.0f;
        const float w01 = (vx1 && vy0) ? wx * ay : 0.0f;
        const float w10 = (vx0 && vy1) ? ax * wy : 0.0f;
        const float w11 = (vx1 && vy1) ? wx * wy : 0.0f;
        const int xc0 = min(max(ix,     0), NPIX - 1);
        const int xc1 = min(max(ix + 1, 0), NPIX - 1);
        const int yc0 = min(max(iy,     0), NPIX - 1);
        const int yc1 = min(max(iy + 1, 0), NPIX - 1);
        acc_corner(pk[(yc0 << 9) + xc0], w00, acc);
        acc_corner(pk[(yc0 << 9) + xc1], w01, acc);
        acc_corner(pk[(yc1 << 9) + xc0], w10, acc);
        acc_corner(pk[(yc1 << 9) + xc1], w11, acc);
    }

    // ---------------- interior loop: s < ie (no clamps/selects) ------------
    for (; s < ie; s += 4) {
        const float sf = (float)s;
        const float fx = fmaf(fxs, sf, fx0);
        const float fy = fmaf(fys, sf, fy0);
        const float x0f = floorf(fx), y0f = floorf(fy);
        const float wx = fx - x0f, wy = fy - y0f;
        const int ix = (int)x0f, iy = (int)y0f;
        const float ax = 1.0f - wx, ay = 1.0f - wy;
        const float w00 = ax * ay;
        const float w01 = wx * ay;
        const float w10 = ax * wy;
        const float w11 = wx * wy;
        const int p0 = (iy << 9) + ix;
        const int p1 = p0 + NPIX;
        acc_corner(pk[p0],     w00, acc);
        acc_corner(pk[p0 + 1], w01, acc);
        acc_corner(pk[p1],     w10, acc);
        acc_corner(pk[p1 + 1], w11, acc);
    }

    // ---------------- border loop 2: s < s_end -----------------------------
    for (; s < s_end; s += 4) {
        const float sf = (float)s;
        const float fx = fmaf(fxs, sf, fx0);
        const float fy = fmaf(fys, sf, fy0);
        const float x0f = floorf(fx), y0f = floorf(fy);
        const float wx = fx - x0f, wy = fy - y0f;
        const int ix = (int)x0f, iy = (int)y0f;
        const float ax = 1.0f - wx, ay = 1.0f - wy;
        const bool vx0 = (unsigned)ix       < (unsigned)NPIX;
        const bool vx1 = (unsigned)(ix + 1) < (unsigned)NPIX;
        const bool vy0 = (unsigned)iy       < (unsigned)NPIX;
        const bool vy1 = (unsigned)(iy + 1) < (unsigned)NPIX;
        const float w00 = (vx0 && vy0) ? ax * ay : 0.0f;
        const float w01 = (vx1 && vy0) ? wx * ay : 0.0f;
        const float w10 = (vx0 && vy1) ? ax * wy : 0.0f;
        const float w11 = (vx1 && vy1) ? wx * wy : 0.0f;
        const int xc0 = min(max(ix,     0), NPIX - 1);
        const int xc1 = min(max(ix + 1, 0), NPIX - 1);
        const int yc0 = min(max(iy,     0), NPIX - 1);
        const int yc1 = min(max(iy + 1, 0), NPIX - 1);
        acc_corner(pk[(yc0 << 9) + xc0], w00, acc);
        acc_corner(pk[(yc0 << 9) + xc1], w01, acc);
        acc_corner(pk[(yc1 << 9) + xc0], w10, acc);
        acc_corner(pk[(yc1 << 9) + xc1], w11, acc);
    }

    // ---- reduce the 4 sample-offset partials per det (lane bits 4,5) ------
#pragma unroll
    for (int b = 0; b < NBATCH; ++b) {
        acc[b] += __shfl_xor(acc[b], 16, 64);
        acc[b] += __shfl_xor(acc[b], 32, 64);
    }

    if (soff == 0) {
#pragma unroll
        for (int b = 0; b < NBATCH; ++b)
            out[((size_t)b * NVIEW + v) * NDET + d] = acc[b] * DT;
    }
}

// ---------------------------------------------------------------------------
// Fallback (original layout, fp32 scalar loads) if ws is too small.
// ---------------------------------------------------------------------------
__global__ __launch_bounds__(256) void projector_kernel_fallback(
    const float* __restrict__ image, const float* __restrict__ views,
    float* __restrict__ out)
{
    const int d = blockIdx.x * blockDim.x + threadIdx.x;
    const int v = blockIdx.y;
    if (d >= NDET) return;

    const float PIX = 0.7433f, ISO = 595.0f;
    const float SDD_ = 595.0f + 490.6f;
    const float DGAM = 1.2858f / SDD_;
    const float FOV  = 512.0f * 0.7433f * 0.70710678f;
    const float T0   = ISO - FOV;
    const float DT   = 2.0f * FOV / (float)NSAMP;

    const float beta  = views[v];
    const float gamma = ((float)d - 0.5f * (float)(NDET - 1)) * DGAM;
    const float sx = ISO * cosf(beta), sy = ISO * sinf(beta);
    const float ang = beta + 3.14159265358979f + gamma;
    const float gx = cosf(ang) / PIX, gy = sinf(ang) / PIX;
    const float cx = sx / PIX + 0.5f * (float)(NPIX - 1);
    const float cy = sy / PIX + 0.5f * (float)(NPIX - 1);

    float acc[NBATCH];
#pragma unroll
    for (int b = 0; b < NBATCH; ++b) acc[b] = 0.0f;

    for (int s = 0; s < NSAMP; ++s) {
        const float t  = fmaf((float)s + 0.5f, DT, T0);
        const float fx = fmaf(gx, t, cx);
        const float fy = fmaf(gy, t, cy);
        const float x0f = floorf(fx), y0f = floorf(fy);
        const float wx = fx - x0f, wy = fy - y0f;
        const int ix = (int)x0f, iy = (int)y0f;
        const float ax = 1.0f - wx, ay = 1.0f - wy;
        const bool vx0 = (unsigned)ix < (unsigned)NPIX;
        const bool vx1 = (unsigned)(ix + 1) < (unsigned)NPIX;
        const bool vy0 = (unsigned)iy < (unsigned)NPIX;
        const bool vy1 = (unsigned)(iy + 1) < (unsigned)NPIX;
        const float w00 = (vx0 && vy0) ? ax * ay : 0.0f;
        const float w01 = (vx1 && vy0) ? wx * ay : 0.0f;
        const float w10 = (vx0 && vy1) ? ax * wy : 0.0f;
        const float w11 = (vx1 && vy1) ? wx * wy : 0.0f;
        const int xc0 = min(max(ix, 0), NPIX - 1);
        const int xc1 = min(max(ix + 1, 0), NPIX - 1);
        const int yc0 = min(max(iy, 0), NPIX - 1);
        const int yc1 = min(max(iy + 1, 0), NPIX - 1);
        const int i00 = (yc0 << 9) + xc0, i01 = (yc0 << 9) + xc1;
        const int i10 = (yc1 << 9) + xc0, i11 = (yc1 << 9) + xc1;
#pragma unroll
        for (int b = 0; b < NBATCH; ++b) {
            const float* img = image + (size_t)b * (NPIX * NPIX);
            acc[b] = fmaf(w00, img[i00], fmaf(w01, img[i01],
                     fmaf(w10, img[i10], fmaf(w11, img[i11], acc[b]))));
        }
    }
#pragma unroll
    for (int b = 0; b < NBATCH; ++b)
        out[((size_t)b * NVIEW + v) * NDET + d] = acc[b] * DT;
}

extern "C" void kernel_launch(void* const* d_in, const int* in_sizes, int n_in,
                              void* d_out, int out_size, void* d_ws, size_t ws_size,
                              hipStream_t stream) {
    const float* image = (const float*)d_in[0];
    const float* views = (const float*)d_in[1];
    float* out = (float*)d_out;

    const size_t packed_bytes = (size_t)NPIX * NPIX * NBATCH * sizeof(__half);

    if (ws_size >= packed_bytes && d_ws != nullptr) {
        __half* packed = (__half*)d_ws;
        repack_kernel<<<dim3((NPIX * NPIX) / 256), dim3(256), 0, stream>>>(image, packed);
        // grid: 64 dets per block (4 waves x 16), one view per blockIdx.y
        projector_kernel<<<dim3(NDET / 64, NVIEW), dim3(256), 0, stream>>>(
            (const int4*)packed, views, out);
    } else {
        projector_kernel_fallback<<<dim3(NDET / 256, NVIEW), dim3(256), 0, stream>>>(image, views, out);
    }
}